// Round 6
// baseline (356.153 us; speedup 1.0000x reference)
//
#include <hip/hip_runtime.h>
#include <hip/hip_bf16.h>

#define NN 50000
#define NE 600000
#define TN 64                       // nodes per dst-tile
#define NT ((NN + TN - 1) / TN)     // 782 tiles
#define CAP 1024                    // bucket capacity (avg 768)

typedef unsigned short u16;
typedef unsigned int u32;
typedef unsigned long long u64;
typedef __attribute__((ext_vector_type(8))) short bf16x8;
typedef __attribute__((ext_vector_type(16))) float f32x16;
typedef __attribute__((ext_vector_type(4))) int int4v;

// ---------- LDS layout (80 KiB -> 2 blocks/CU) ----------
#define SM_AB   0        // 16K: pr [64 e][128 k] (stage) / hid [64 e][128 n1] / aggL [64 d][128 n]
#define SM_MSGT 16384    // 16K: msgt [128 n2][64 e] 128B rows / upd: hiddenU [64][128] 256B rows
#define SM_TT   32768    // 16K: tt [128 n1][64 d] 128B rows
#define SM_SB0  49152    // 16K: S0 [64 d][64 e] 8K + St0 [64 e][64 d] 8K
#define SM_SB1  65536    // 16K: S1+St1  (prologue & upd phase: ht [64 node][128 k])
#define SMEM_TOTAL 81920

// LDS-only barrier: no vmcnt drain (prefetch stays in flight)
__device__ __forceinline__ void bar_lds() {
    asm volatile("s_waitcnt lgkmcnt(0)" ::: "memory");
    __builtin_amdgcn_s_barrier();
}

__device__ __forceinline__ u16 f2b(float x) {
    __hip_bfloat16 b = __float2bfloat16(x);
    union { __hip_bfloat16 b; u16 u; } c; c.b = b; return c.u;
}
__device__ __forceinline__ int4v zero4() {
    int4v v; v[0]=0; v[1]=0; v[2]=0; v[3]=0; return v;
}
__device__ __forceinline__ f32x16 zero16() {
    f32x16 z;
#pragma unroll
    for (int i = 0; i < 16; ++i) z[i] = 0.f;
    return z;
}
__device__ __forceinline__ int4v cvt8(const float* __restrict__ p) {
    const float4* q = (const float4*)p;
    float4 f0 = q[0], f1 = q[1];
    union { u16 u[8]; int4v v; } r;
    r.u[0]=f2b(f0.x); r.u[1]=f2b(f0.y); r.u[2]=f2b(f0.z); r.u[3]=f2b(f0.w);
    r.u[4]=f2b(f1.x); r.u[5]=f2b(f1.y); r.u[6]=f2b(f1.z); r.u[7]=f2b(f1.w);
    return r.v;
}
__device__ __forceinline__ u64 pack4(float a, float b, float c, float d) {
    union { u16 u[4]; u64 q; } r;
    r.u[0]=f2b(a); r.u[1]=f2b(b); r.u[2]=f2b(c); r.u[3]=f2b(d); return r.q;
}
__device__ __forceinline__ f32x16 mfma16(bf16x8 a, bf16x8 b, f32x16 c) {
    return __builtin_amdgcn_mfma_f32_32x32x16_bf16(a, b, c, 0, 0, 0);
}
// 256B-row buffers (16 chunks), 4-bit XOR swizzle
__device__ __forceinline__ bf16x8 ld256(const char* base, int row, int c) {
    return *(const bf16x8*)(base + row * 256 + ((c ^ (row & 15)) << 4));
}
// 128B-row buffers (8 chunks), 3-bit XOR swizzle
__device__ __forceinline__ bf16x8 ld128r(const char* base, int row, int c) {
    return *(const bf16x8*)(base + row * 128 + ((c ^ (row & 7)) << 4));
}

// ---------------- prep: weights -> bf16 transposed; h -> bf16 ----------------
__global__ void prep_kernel(const float* __restrict__ h,
                            const float* __restrict__ W1m, const float* __restrict__ W2m,
                            const float* __restrict__ W1u, const float* __restrict__ W2u,
                            u16* __restrict__ w1tm, u16* __restrict__ w2tm,
                            u16* __restrict__ w1tu, u16* __restrict__ w2tu,
                            u16* __restrict__ hbuf, int do_h)
{
    int tid = blockIdx.x * blockDim.x + threadIdx.x;
    int stride = gridDim.x * blockDim.x;
    for (int i = tid; i < 128 * 256; i += stride) {
        int n = i >> 8, k = i & 255;
        w1tm[i] = f2b(W1m[k * 128 + n]);
        w1tu[i] = f2b(W1u[k * 128 + n]);
    }
    for (int i = tid; i < 128 * 128; i += stride) {
        int n = i >> 7, k = i & 127;
        w2tm[i] = f2b(W2m[k * 128 + n]);
        w2tu[i] = f2b(W2u[k * 128 + n]);
    }
    if (do_h) {
        for (int i = tid; i < NN * 128 / 8; i += stride)
            *(int4v*)(hbuf + (size_t)i * 8) = cvt8(h + (size_t)i * 8);
    }
}

// ---------------- scatter: counting-bucket edges by dst tile ----------------
__global__ __launch_bounds__(256) void scatter_kernel(
    const int* __restrict__ edges, u32* __restrict__ elist, int* __restrict__ cursor)
{
    __shared__ int lcnt[NT];
    const int e0 = blockIdx.x * 2048;
    for (int i = threadIdx.x; i < NT; i += 256) lcnt[i] = 0;
    __syncthreads();
#pragma unroll
    for (int k = 0; k < 8; ++k) {
        int e = e0 + k * 256 + threadIdx.x;
        if (e < NE) atomicAdd(&lcnt[edges[2 * e + 1] >> 6], 1);
    }
    __syncthreads();
    for (int i = threadIdx.x; i < NT; i += 256) {
        int cn = lcnt[i];
        if (cn > 0) lcnt[i] = atomicAdd(&cursor[i], cn);
    }
    __syncthreads();
#pragma unroll
    for (int k = 0; k < 8; ++k) {
        int e = e0 + k * 256 + threadIdx.x;
        if (e < NE) {
            int s = edges[2 * e], d = edges[2 * e + 1];
            int bin = d >> 6;
            int pos = atomicAdd(&lcnt[bin], 1);
            if (pos < CAP) elist[(size_t)bin * CAP + pos] = (u32)s | ((u32)(d & 63) << 16);
        }
    }
}

// ---------------- fused per-dst-tile ----------------
__global__ __launch_bounds__(512, 4) void fused_kernel(
    const float* __restrict__ h, const u16* __restrict__ hb, int use_hb,
    const u32* __restrict__ elist, const int* __restrict__ cursor,
    const u16* __restrict__ w1m, const u16* __restrict__ w2m,
    const u16* __restrict__ w1u, const u16* __restrict__ w2u,
    const float* __restrict__ b1m, const float* __restrict__ b2m,
    const float* __restrict__ b1u, const float* __restrict__ b2u,
    float* __restrict__ outp)
{
    extern __shared__ char sm[];
    char* ab   = sm + SM_AB;      // pr / hid / aggL
    char* msgt = sm + SM_MSGT;    // msgt / hiddenU
    char* tt   = sm + SM_TT;
    char* htp  = sm + SM_SB1;     // ht (prologue + upd); S/St buf1 during loop

    const int tid  = threadIdx.x;
    const int lane = tid & 63;
    const int wid  = tid >> 6;
    const int wn   = wid >> 1;          // n-block 0..3
    const int wb   = wid & 1;           // e/d/node block 0..1
    const int l31  = lane & 31;
    const int kg   = lane >> 5;
    const int nrow = wn * 32 + l31;     // output-feature index
    const int ecol = wb * 32 + l31;     // edge/dst/node index

    const int bin = blockIdx.x;
    const int n0  = bin * TN;
    int size = cursor[bin]; if (size > CAP) size = CAP;
    const u32* el = elist + (size_t)bin * CAP;
    const int nchunk = (size + 63) >> 6;

    // ---- weight fragments: global -> registers ----
    bf16x8 w1f[8], w2f[8], wtf[8];
#pragma unroll
    for (int kk = 0; kk < 8; ++kk) {
        w1f[kk] = *(const bf16x8*)(w1m + nrow * 256 + (kk * 2 + kg) * 8);       // src half
        wtf[kk] = *(const bf16x8*)(w1m + nrow * 256 + (16 + kk * 2 + kg) * 8);  // dst half
        w2f[kk] = *(const bf16x8*)(w2m + nrow * 128 + (kk * 2 + kg) * 8);
    }
    float b1r[16];
#pragma unroll
    for (int r = 0; r < 16; ++r) b1r[r] = b1m[wn * 32 + (r & 3) + 8 * (r >> 2) + 4 * kg];
    const float b2ms = b2m[nrow];

    // ---- stage ht (dst-tile h rows) into SB1 region ----
    for (int i = tid; i < 1024; i += 512) {
        int row = i >> 4, c = i & 15;
        int node = n0 + row;
        int4v v = zero4();
        if (node < NN) {
            if (use_hb) v = *(const int4v*)(hb + (size_t)node * 128 + c * 8);
            else        v = cvt8(h + (size_t)node * 128 + c * 8);
        }
        *(int4v*)(htp + row * 256 + ((c ^ (row & 15)) << 4)) = v;
    }
    // zero S/St buffer 0
    {
        char* z = sm + SM_SB0 + tid * 32;
        *(int4v*)z = zero4(); *(int4v*)(z + 16) = zero4();
    }

    // ones writer (wave 0 only): S[d][e]=1, St[e][d]=1 for valid edges
    auto put_ones = [&](int buf, u32 dle_c, int cb2) {
        if (cb2 + lane < size) {
            int d = (int)((dle_c >> 16) & 63);
            char* Sb  = sm + SM_SB0 + buf * 16384;
            char* Stb = Sb + 8192;
            *(u16*)(Sb  + d * 128 + (((lane >> 3) ^ (d & 7)) << 4) + (lane & 7) * 2) = 0x3F80;
            *(u16*)(Stb + lane * 128 + (((d >> 3) ^ (lane & 7)) << 4) + (d & 7) * 2) = 0x3F80;
        }
    };

    // src gather staging: thread -> rows (tid>>4, +32) x 16B chunk (tid&15)
    const int s_row0 = tid >> 4, s_cc = tid & 15;
    auto stage_load = [&](u32 dle_c, int cb2, int4v& v0, int4v& v1) {
        int s0 = ((int)__shfl((int)dle_c, s_row0, 64)) & 0xFFFF;
        int s1 = ((int)__shfl((int)dle_c, s_row0 + 32, 64)) & 0xFFFF;
        v0 = zero4(); v1 = zero4();
        if (cb2 + s_row0 < size)
            v0 = use_hb ? *(const int4v*)(hb + (size_t)s0 * 128 + s_cc * 8)
                        : cvt8(h + (size_t)s0 * 128 + s_cc * 8);
        if (cb2 + s_row0 + 32 < size)
            v1 = use_hb ? *(const int4v*)(hb + (size_t)s1 * 128 + s_cc * 8)
                        : cvt8(h + (size_t)s1 * 128 + s_cc * 8);
    };
    auto stage_write = [&](int4v v0, int4v v1) {
        *(int4v*)(ab + s_row0 * 256 + ((s_cc ^ (s_row0 & 15)) << 4)) = v0;
        int r1 = s_row0 + 32;
        *(int4v*)(ab + r1 * 256 + ((s_cc ^ (r1 & 15)) << 4)) = v1;
    };

    u32 dle = (lane < size) ? el[lane] : 0u;     // chunk 0 edge records
    if (nchunk > 0) {
        int4v v0, v1;
        stage_load(dle, 0, v0, v1);
        stage_write(v0, v1);
    }
    __syncthreads();   // ht / S0-zero / pr0 ready (full drain once is fine)

    // ---- T-compute: Tt[n1][d] = sum_k W1dst[n1][k] * ht[d][k] ----
    {
        f32x16 t = zero16();
#pragma unroll
        for (int kk = 0; kk < 8; ++kk)
            t = mfma16(wtf[kk], ld256(htp, ecol, kk * 2 + kg), t);
#pragma unroll
        for (int r = 0; r < 16; ++r) {
            int n1 = wn * 32 + (r & 3) + 8 * (r >> 2) + 4 * kg;
            *(u16*)(tt + n1 * 128 + (((ecol >> 3) ^ (n1 & 7)) << 4) + (ecol & 7) * 2) = f2b(t[r]);
        }
    }
    if (wid == 0) put_ones(0, dle, 0);
    bar_lds();   // Tt + S0/St0 ready; ht reads done (SB1 free for buf1)

    // ---- chunk loop: 4 phases, 4 LDS-only barriers ----
    f32x16 aggT = zero16();
    for (int c = 0; c < nchunk; ++c) {
        const int cb = c << 6;
        const bool havepf = (c + 1 < nchunk);
        const int cur = c & 1, nxt = cur ^ 1;
        char* Scur  = sm + SM_SB0 + cur * 16384;
        char* Stcur = Scur + 8192;

        u32 dle_next = (havepf && (cb + 64 + lane < size)) ? el[cb + 64 + lane] : 0u;

        // ---- P0: GEMM1 (swapped) -> acc[n1][e] ----
        f32x16 acc = zero16();
#pragma unroll
        for (int kk = 0; kk < 8; ++kk)
            acc = mfma16(w1f[kk], ld256(ab, ecol, kk * 2 + kg), acc);          // src half (pr)
#pragma unroll
        for (int kk = 0; kk < 4; ++kk)
            acc = mfma16(ld128r(tt, nrow, kk * 2 + kg),
                         ld128r(Stcur, ecol, kk * 2 + kg), acc);               // dst half Tt@St
        bar_lds();   // ALL waves done reading pr (ab) -> safe to overwrite as hid

        // ---- P1: epi1 -> hidden into ab (alias); zero next S buffer ----
        {
            char* z = sm + SM_SB0 + nxt * 16384 + tid * 32;
            *(int4v*)z = zero4(); *(int4v*)(z + 16) = zero4();
        }
#pragma unroll
        for (int rq = 0; rq < 4; ++rq) {     // hidden[e][n1], packed b64
            int cch = wn * 4 + rq;
            u64 q = pack4(fmaxf(acc[4 * rq + 0] + b1r[4 * rq + 0], 0.f),
                          fmaxf(acc[4 * rq + 1] + b1r[4 * rq + 1], 0.f),
                          fmaxf(acc[4 * rq + 2] + b1r[4 * rq + 2], 0.f),
                          fmaxf(acc[4 * rq + 3] + b1r[4 * rq + 3], 0.f));
            *(u64*)(ab + ecol * 256 + ((cch ^ (ecol & 15)) << 4) + 8 * kg) = q;
        }
        bar_lds();   // hidden ready

        // ---- P2: GEMM2 (direct) -> msg; epi2 -> msgt; ones(next); gather issue ----
        int4v v0, v1;
        if (havepf) stage_load(dle_next, cb + 64, v0, v1);   // global loads in flight
        f32x16 c2 = zero16();
#pragma unroll
        for (int kk = 0; kk < 8; ++kk)
            c2 = mfma16(ld256(ab, ecol, kk * 2 + kg), w2f[kk], c2);
#pragma unroll
        for (int rq = 0; rq < 4; ++rq) {     // msgt[n2][e], packed b64 (+b2)
            int cch = wb * 4 + rq;
            u64 q = pack4(c2[4 * rq + 0] + b2ms, c2[4 * rq + 1] + b2ms,
                          c2[4 * rq + 2] + b2ms, c2[4 * rq + 3] + b2ms);
            *(u64*)(msgt + nrow * 128 + ((cch ^ (nrow & 7)) << 4) + 8 * kg) = q;
        }
        if (wid == 0 && havepf) put_ones(nxt, dle_next, cb + 64);
        bar_lds();   // msgt ready; hid (ab) reads done

        // ---- P3: aggT += msgt @ S; stage next pr into ab ----
#pragma unroll
        for (int kk = 0; kk < 4; ++kk)
            aggT = mfma16(ld128r(msgt, nrow, kk * 2 + kg),
                          ld128r(Scur, ecol, kk * 2 + kg), aggT);
        if (havepf) stage_write(v0, v1);
        dle = dle_next;
        bar_lds();   // next pr ready / msgt,S reads done
    }

    // ---- upd phase ----
    bf16x8 wuf[16], w2uf[8];
#pragma unroll
    for (int kk = 0; kk < 16; ++kk)
        wuf[kk] = *(const bf16x8*)(w1u + nrow * 256 + (kk * 2 + kg) * 8);
#pragma unroll
    for (int kk = 0; kk < 8; ++kk)
        w2uf[kk] = *(const bf16x8*)(w2u + nrow * 128 + (kk * 2 + kg) * 8);
    float b1ur[16];
#pragma unroll
    for (int r = 0; r < 16; ++r) b1ur[r] = b1u[wn * 32 + (r & 3) + 8 * (r >> 2) + 4 * kg];
    const float b2us = b2u[nrow];

    // aggT regs -> aggL [d][n] into ab (pr dead); re-stage ht into SB1 (S/St dead)
#pragma unroll
    for (int rq = 0; rq < 4; ++rq) {
        int cch = wn * 4 + rq;
        u64 q = pack4(aggT[4 * rq + 0], aggT[4 * rq + 1], aggT[4 * rq + 2], aggT[4 * rq + 3]);
        *(u64*)(ab + ecol * 256 + ((cch ^ (ecol & 15)) << 4) + 8 * kg) = q;
    }
    for (int i = tid; i < 1024; i += 512) {
        int row = i >> 4, c = i & 15;
        int node = n0 + row;
        int4v v = zero4();
        if (node < NN) {
            if (use_hb) v = *(const int4v*)(hb + (size_t)node * 128 + c * 8);
            else        v = cvt8(h + (size_t)node * 128 + c * 8);
        }
        *(int4v*)(htp + row * 256 + ((c ^ (row & 15)) << 4)) = v;
    }
    __syncthreads();   // aggL + ht ready (vmcnt drain fine here, once)

    // upd GEMM1 (swapped): au[n1][node] = W1u @ [ht | aggL]^T
    {
        f32x16 au = zero16();
#pragma unroll
        for (int kk = 0; kk < 8; ++kk)
            au = mfma16(wuf[kk], ld256(htp, ecol, kk * 2 + kg), au);
#pragma unroll
        for (int kk = 0; kk < 8; ++kk)
            au = mfma16(wuf[8 + kk], ld256(ab, ecol, kk * 2 + kg), au);
        // epiU1 -> hiddenU[node][n1] into msgt region (256B rows)
#pragma unroll
        for (int rq = 0; rq < 4; ++rq) {
            int cch = wn * 4 + rq;
            u64 q = pack4(fmaxf(au[4 * rq + 0] + b1ur[4 * rq + 0], 0.f),
                          fmaxf(au[4 * rq + 1] + b1ur[4 * rq + 1], 0.f),
                          fmaxf(au[4 * rq + 2] + b1ur[4 * rq + 2], 0.f),
                          fmaxf(au[4 * rq + 3] + b1ur[4 * rq + 3], 0.f));
            *(u64*)(msgt + ecol * 256 + ((cch ^ (ecol & 15)) << 4) + 8 * kg) = q;
        }
    }
    bar_lds();

    // upd GEMM2 (direct): out[node][n2] = hiddenU @ W2u + b2u + h
    {
        f32x16 cu = zero16();
#pragma unroll
        for (int kk = 0; kk < 8; ++kk)
            cu = mfma16(ld256(msgt, ecol, kk * 2 + kg), w2uf[kk], cu);
#pragma unroll
        for (int r = 0; r < 16; ++r) {
            int node = wb * 32 + (r & 3) + 8 * (r >> 2) + 4 * kg;
            int ng = n0 + node;
            if (ng < NN) {
                size_t o = (size_t)ng * 128 + nrow;
                outp[o] = cu[r] + b2us + h[o];
            }
        }
    }
}

extern "C" void kernel_launch(void* const* d_in, const int* in_sizes, int n_in,
                              void* d_out, int out_size, void* d_ws, size_t ws_size,
                              hipStream_t stream) {
    const float* h   = (const float*)d_in[0];
    const int* edges = (const int*)d_in[1];
    const float* W1m = (const float*)d_in[2];
    const float* b1m = (const float*)d_in[3];
    const float* W2m = (const float*)d_in[4];
    const float* b2m = (const float*)d_in[5];
    const float* W1u = (const float*)d_in[6];
    const float* b1u = (const float*)d_in[7];
    const float* W2u = (const float*)d_in[8];
    const float* b2u = (const float*)d_in[9];
    float* out = (float*)d_out;

    char* ws = (char*)d_ws;
    u16* w1tm  = (u16*)(ws + 0);
    u16* w2tm  = (u16*)(ws + 65536);
    u16* w1tu  = (u16*)(ws + 98304);
    u16* w2tu  = (u16*)(ws + 163840);
    int* curs  = (int*)(ws + 196608);
    u32* elist = (u32*)(ws + 200704);    // NT*CAP*4 = 3,203,072
    u16* hb    = (u16*)(ws + 3403776);   // 12,800,000
    int use_hb = (ws_size >= 3403776ull + (size_t)NN * 128 * 2) ? 1 : 0;

    (void)hipFuncSetAttribute((const void*)fused_kernel,
                              hipFuncAttributeMaxDynamicSharedMemorySize, SMEM_TOTAL);

    hipMemsetAsync(curs, 0, NT * sizeof(int), stream);
    prep_kernel<<<512, 256, 0, stream>>>(h, W1m, W2m, W1u, W2u,
                                         w1tm, w2tm, w1tu, w2tu, hb, use_hb);
    scatter_kernel<<<(NE + 2047) / 2048, 256, 0, stream>>>(edges, elist, curs);
    fused_kernel<<<NT, 512, SMEM_TOTAL, stream>>>(h, hb, use_hb, elist, curs,
                                                  w1tm, w2tm, w1tu, w2tu,
                                                  b1m, b2m, b1u, b2u, out);
}

// Round 7
// 199.918 us; speedup vs baseline: 1.7815x; 1.7815x over previous
//
#include <hip/hip_runtime.h>
#include <hip/hip_bf16.h>

#define NN 50000
#define NE 600000
#define TN 64                       // nodes per dst-tile
#define NT ((NN + TN - 1) / TN)     // 782 tiles
#define CAP 1024                    // bucket capacity (avg 768)

typedef unsigned short u16;
typedef unsigned int u32;
typedef unsigned long long u64;
typedef __attribute__((ext_vector_type(8))) short bf16x8;
typedef __attribute__((ext_vector_type(16))) float f32x16;
typedef __attribute__((ext_vector_type(4))) int int4v;

// ---------- LDS layout (80 KiB -> 2 blocks/CU) ----------
#define SM_AB   0        // 16K: pr [64 e][128 k] (stage) / hid [64 e][128 n1] / aggL [64 d][128 n]
#define SM_MSGT 16384    // 16K: msgt [128 n2][64 e] 128B rows / upd: hiddenU [64][128] 256B rows
#define SM_TT   32768    // 16K: tt [128 n1][64 d] 128B rows
#define SM_SB0  49152    // 16K: S0 [64 d][64 e] 8K + St0 [64 e][64 d] 8K
#define SM_SB1  65536    // 16K: S1+St1  (prologue & upd phase: ht [64 node][128 k])
#define SMEM_TOTAL 81920

// LDS-only barrier: no vmcnt drain (prefetch stays in flight)
__device__ __forceinline__ void bar_lds() {
    asm volatile("s_waitcnt lgkmcnt(0)" ::: "memory");
    __builtin_amdgcn_s_barrier();
}

__device__ __forceinline__ u16 f2b(float x) {
    __hip_bfloat16 b = __float2bfloat16(x);
    union { __hip_bfloat16 b; u16 u; } c; c.b = b; return c.u;
}
__device__ __forceinline__ int4v zero4() {
    int4v v; v[0]=0; v[1]=0; v[2]=0; v[3]=0; return v;
}
__device__ __forceinline__ f32x16 zero16() {
    f32x16 z;
#pragma unroll
    for (int i = 0; i < 16; ++i) z[i] = 0.f;
    return z;
}
__device__ __forceinline__ int4v cvt8(const float* __restrict__ p) {
    const float4* q = (const float4*)p;
    float4 f0 = q[0], f1 = q[1];
    union { u16 u[8]; int4v v; } r;
    r.u[0]=f2b(f0.x); r.u[1]=f2b(f0.y); r.u[2]=f2b(f0.z); r.u[3]=f2b(f0.w);
    r.u[4]=f2b(f1.x); r.u[5]=f2b(f1.y); r.u[6]=f2b(f1.z); r.u[7]=f2b(f1.w);
    return r.v;
}
__device__ __forceinline__ u64 pack4(float a, float b, float c, float d) {
    union { u16 u[4]; u64 q; } r;
    r.u[0]=f2b(a); r.u[1]=f2b(b); r.u[2]=f2b(c); r.u[3]=f2b(d); return r.q;
}
__device__ __forceinline__ f32x16 mfma16(bf16x8 a, bf16x8 b, f32x16 c) {
    return __builtin_amdgcn_mfma_f32_32x32x16_bf16(a, b, c, 0, 0, 0);
}
// 256B-row buffers (16 chunks), 4-bit XOR swizzle
__device__ __forceinline__ bf16x8 ld256(const char* base, int row, int c) {
    return *(const bf16x8*)(base + row * 256 + ((c ^ (row & 15)) << 4));
}
// 128B-row buffers (8 chunks), 3-bit XOR swizzle
__device__ __forceinline__ bf16x8 ld128r(const char* base, int row, int c) {
    return *(const bf16x8*)(base + row * 128 + ((c ^ (row & 7)) << 4));
}

// ---------------- prep: weights -> bf16 transposed; h -> bf16 ----------------
__global__ void prep_kernel(const float* __restrict__ h,
                            const float* __restrict__ W1m, const float* __restrict__ W2m,
                            const float* __restrict__ W1u, const float* __restrict__ W2u,
                            u16* __restrict__ w1tm, u16* __restrict__ w2tm,
                            u16* __restrict__ w1tu, u16* __restrict__ w2tu,
                            u16* __restrict__ hbuf, int do_h)
{
    int tid = blockIdx.x * blockDim.x + threadIdx.x;
    int stride = gridDim.x * blockDim.x;
    for (int i = tid; i < 128 * 256; i += stride) {
        int n = i >> 8, k = i & 255;
        w1tm[i] = f2b(W1m[k * 128 + n]);
        w1tu[i] = f2b(W1u[k * 128 + n]);
    }
    for (int i = tid; i < 128 * 128; i += stride) {
        int n = i >> 7, k = i & 127;
        w2tm[i] = f2b(W2m[k * 128 + n]);
        w2tu[i] = f2b(W2u[k * 128 + n]);
    }
    if (do_h) {
        for (int i = tid; i < NN * 128 / 8; i += stride)
            *(int4v*)(hbuf + (size_t)i * 8) = cvt8(h + (size_t)i * 8);
    }
}

// ---------------- scatter: counting-bucket edges by dst tile ----------------
__global__ __launch_bounds__(256) void scatter_kernel(
    const int* __restrict__ edges, u32* __restrict__ elist, int* __restrict__ cursor)
{
    __shared__ int lcnt[NT];
    const int e0 = blockIdx.x * 2048;
    for (int i = threadIdx.x; i < NT; i += 256) lcnt[i] = 0;
    __syncthreads();
#pragma unroll
    for (int k = 0; k < 8; ++k) {
        int e = e0 + k * 256 + threadIdx.x;
        if (e < NE) atomicAdd(&lcnt[edges[2 * e + 1] >> 6], 1);
    }
    __syncthreads();
    for (int i = threadIdx.x; i < NT; i += 256) {
        int cn = lcnt[i];
        if (cn > 0) lcnt[i] = atomicAdd(&cursor[i], cn);
    }
    __syncthreads();
#pragma unroll
    for (int k = 0; k < 8; ++k) {
        int e = e0 + k * 256 + threadIdx.x;
        if (e < NE) {
            int s = edges[2 * e], d = edges[2 * e + 1];
            int bin = d >> 6;
            int pos = atomicAdd(&lcnt[bin], 1);
            if (pos < CAP) elist[(size_t)bin * CAP + pos] = (u32)s | ((u32)(d & 63) << 16);
        }
    }
}

// ---------------- fused per-dst-tile ----------------
__global__ __launch_bounds__(512, 2) void fused_kernel(
    const float* __restrict__ h, const u16* __restrict__ hb, int use_hb,
    const u32* __restrict__ elist, const int* __restrict__ cursor,
    const u16* __restrict__ w1m, const u16* __restrict__ w2m,
    const u16* __restrict__ w1u, const u16* __restrict__ w2u,
    const float* __restrict__ b1m, const float* __restrict__ b2m,
    const float* __restrict__ b1u, const float* __restrict__ b2u,
    float* __restrict__ outp)
{
    extern __shared__ char sm[];
    char* ab   = sm + SM_AB;      // pr / hid / aggL
    char* msgt = sm + SM_MSGT;    // msgt / hiddenU
    char* tt   = sm + SM_TT;
    char* htp  = sm + SM_SB1;     // ht (prologue + upd); S/St buf1 during loop

    const int tid  = threadIdx.x;
    const int lane = tid & 63;
    const int wid  = tid >> 6;
    const int wn   = wid >> 1;          // n-block 0..3
    const int wb   = wid & 1;           // e/d/node block 0..1
    const int l31  = lane & 31;
    const int kg   = lane >> 5;
    const int nrow = wn * 32 + l31;     // output-feature index
    const int ecol = wb * 32 + l31;     // edge/dst/node index

    const int bin = blockIdx.x;
    const int n0  = bin * TN;
    int size = cursor[bin]; if (size > CAP) size = CAP;
    const u32* el = elist + (size_t)bin * CAP;
    const int nchunk = (size + 63) >> 6;

    // ---- weight fragments: global -> registers ----
    bf16x8 w1f[8], w2f[8], wtf[8];
#pragma unroll
    for (int kk = 0; kk < 8; ++kk) {
        w1f[kk] = *(const bf16x8*)(w1m + nrow * 256 + (kk * 2 + kg) * 8);       // src half
        wtf[kk] = *(const bf16x8*)(w1m + nrow * 256 + (16 + kk * 2 + kg) * 8);  // dst half
        w2f[kk] = *(const bf16x8*)(w2m + nrow * 128 + (kk * 2 + kg) * 8);
    }
    float b1r[16];
#pragma unroll
    for (int r = 0; r < 16; ++r) b1r[r] = b1m[wn * 32 + (r & 3) + 8 * (r >> 2) + 4 * kg];
    const float b2ms = b2m[nrow];

    // ---- stage ht (dst-tile h rows) into SB1 region ----
    for (int i = tid; i < 1024; i += 512) {
        int row = i >> 4, c = i & 15;
        int node = n0 + row;
        int4v v = zero4();
        if (node < NN) {
            if (use_hb) v = *(const int4v*)(hb + (size_t)node * 128 + c * 8);
            else        v = cvt8(h + (size_t)node * 128 + c * 8);
        }
        *(int4v*)(htp + row * 256 + ((c ^ (row & 15)) << 4)) = v;
    }
    // zero S/St buffer 0
    {
        char* z = sm + SM_SB0 + tid * 32;
        *(int4v*)z = zero4(); *(int4v*)(z + 16) = zero4();
    }

    // ones writer (wave 0 only): S[d][e]=1, St[e][d]=1 for valid edges
    auto put_ones = [&](int buf, u32 dle_c, int cb2) {
        if (cb2 + lane < size) {
            int d = (int)((dle_c >> 16) & 63);
            char* Sb  = sm + SM_SB0 + buf * 16384;
            char* Stb = Sb + 8192;
            *(u16*)(Sb  + d * 128 + (((lane >> 3) ^ (d & 7)) << 4) + (lane & 7) * 2) = 0x3F80;
            *(u16*)(Stb + lane * 128 + (((d >> 3) ^ (lane & 7)) << 4) + (d & 7) * 2) = 0x3F80;
        }
    };

    // src gather staging: thread -> rows (tid>>4, +32) x 16B chunk (tid&15)
    const int s_row0 = tid >> 4, s_cc = tid & 15;
    auto stage_load = [&](u32 dle_c, int cb2, int4v& v0, int4v& v1) {
        int s0 = ((int)__shfl((int)dle_c, s_row0, 64)) & 0xFFFF;
        int s1 = ((int)__shfl((int)dle_c, s_row0 + 32, 64)) & 0xFFFF;
        v0 = zero4(); v1 = zero4();
        if (cb2 + s_row0 < size)
            v0 = use_hb ? *(const int4v*)(hb + (size_t)s0 * 128 + s_cc * 8)
                        : cvt8(h + (size_t)s0 * 128 + s_cc * 8);
        if (cb2 + s_row0 + 32 < size)
            v1 = use_hb ? *(const int4v*)(hb + (size_t)s1 * 128 + s_cc * 8)
                        : cvt8(h + (size_t)s1 * 128 + s_cc * 8);
    };
    auto stage_write = [&](int4v v0, int4v v1) {
        *(int4v*)(ab + s_row0 * 256 + ((s_cc ^ (s_row0 & 15)) << 4)) = v0;
        int r1 = s_row0 + 32;
        *(int4v*)(ab + r1 * 256 + ((s_cc ^ (r1 & 15)) << 4)) = v1;
    };

    u32 dle = (lane < size) ? el[lane] : 0u;     // chunk 0 edge records
    if (nchunk > 0) {
        int4v v0, v1;
        stage_load(dle, 0, v0, v1);
        stage_write(v0, v1);
    }
    __syncthreads();   // ht / S0-zero / pr0 ready (full drain once is fine)

    // ---- T-compute: Tt[n1][d] = sum_k W1dst[n1][k] * ht[d][k] ----
    {
        f32x16 t = zero16();
#pragma unroll
        for (int kk = 0; kk < 8; ++kk)
            t = mfma16(wtf[kk], ld256(htp, ecol, kk * 2 + kg), t);
#pragma unroll
        for (int r = 0; r < 16; ++r) {
            int n1 = wn * 32 + (r & 3) + 8 * (r >> 2) + 4 * kg;
            *(u16*)(tt + n1 * 128 + (((ecol >> 3) ^ (n1 & 7)) << 4) + (ecol & 7) * 2) = f2b(t[r]);
        }
    }
    if (wid == 0) put_ones(0, dle, 0);
    bar_lds();   // Tt + S0/St0 ready; ht reads done (SB1 free for buf1)

    // ---- chunk loop: 4 phases, 4 LDS-only barriers ----
    f32x16 aggT = zero16();
    for (int c = 0; c < nchunk; ++c) {
        const int cb = c << 6;
        const bool havepf = (c + 1 < nchunk);
        const int cur = c & 1, nxt = cur ^ 1;
        char* Scur  = sm + SM_SB0 + cur * 16384;
        char* Stcur = Scur + 8192;

        u32 dle_next = (havepf && (cb + 64 + lane < size)) ? el[cb + 64 + lane] : 0u;

        // ---- P0: GEMM1 (swapped) -> acc[n1][e] ----
        f32x16 acc = zero16();
#pragma unroll
        for (int kk = 0; kk < 8; ++kk)
            acc = mfma16(w1f[kk], ld256(ab, ecol, kk * 2 + kg), acc);          // src half (pr)
#pragma unroll
        for (int kk = 0; kk < 4; ++kk)
            acc = mfma16(ld128r(tt, nrow, kk * 2 + kg),
                         ld128r(Stcur, ecol, kk * 2 + kg), acc);               // dst half Tt@St
        bar_lds();   // ALL waves done reading pr (ab) -> safe to overwrite as hid

        // ---- P1: epi1 -> hidden into ab (alias); zero next S buffer ----
        {
            char* z = sm + SM_SB0 + nxt * 16384 + tid * 32;
            *(int4v*)z = zero4(); *(int4v*)(z + 16) = zero4();
        }
#pragma unroll
        for (int rq = 0; rq < 4; ++rq) {     // hidden[e][n1], packed b64
            int cch = wn * 4 + rq;
            u64 q = pack4(fmaxf(acc[4 * rq + 0] + b1r[4 * rq + 0], 0.f),
                          fmaxf(acc[4 * rq + 1] + b1r[4 * rq + 1], 0.f),
                          fmaxf(acc[4 * rq + 2] + b1r[4 * rq + 2], 0.f),
                          fmaxf(acc[4 * rq + 3] + b1r[4 * rq + 3], 0.f));
            *(u64*)(ab + ecol * 256 + ((cch ^ (ecol & 15)) << 4) + 8 * kg) = q;
        }
        bar_lds();   // hidden ready

        // ---- P2: GEMM2 (direct) -> msg; epi2 -> msgt; ones(next); gather issue ----
        int4v v0, v1;
        if (havepf) stage_load(dle_next, cb + 64, v0, v1);   // global loads in flight
        f32x16 c2 = zero16();
#pragma unroll
        for (int kk = 0; kk < 8; ++kk)
            c2 = mfma16(ld256(ab, ecol, kk * 2 + kg), w2f[kk], c2);
#pragma unroll
        for (int rq = 0; rq < 4; ++rq) {     // msgt[n2][e], packed b64 (+b2)
            int cch = wb * 4 + rq;
            u64 q = pack4(c2[4 * rq + 0] + b2ms, c2[4 * rq + 1] + b2ms,
                          c2[4 * rq + 2] + b2ms, c2[4 * rq + 3] + b2ms);
            *(u64*)(msgt + nrow * 128 + ((cch ^ (nrow & 7)) << 4) + 8 * kg) = q;
        }
        if (wid == 0 && havepf) put_ones(nxt, dle_next, cb + 64);
        bar_lds();   // msgt ready; hid (ab) reads done

        // ---- P3: aggT += msgt @ S; stage next pr into ab ----
#pragma unroll
        for (int kk = 0; kk < 4; ++kk)
            aggT = mfma16(ld128r(msgt, nrow, kk * 2 + kg),
                          ld128r(Scur, ecol, kk * 2 + kg), aggT);
        if (havepf) stage_write(v0, v1);
        dle = dle_next;
        bar_lds();   // next pr ready / msgt,S reads done
    }

    // ---- upd phase ----
    bf16x8 wuf[16], w2uf[8];
#pragma unroll
    for (int kk = 0; kk < 16; ++kk)
        wuf[kk] = *(const bf16x8*)(w1u + nrow * 256 + (kk * 2 + kg) * 8);
#pragma unroll
    for (int kk = 0; kk < 8; ++kk)
        w2uf[kk] = *(const bf16x8*)(w2u + nrow * 128 + (kk * 2 + kg) * 8);
    float b1ur[16];
#pragma unroll
    for (int r = 0; r < 16; ++r) b1ur[r] = b1u[wn * 32 + (r & 3) + 8 * (r >> 2) + 4 * kg];
    const float b2us = b2u[nrow];

    // aggT regs -> aggL [d][n] into ab (pr dead); re-stage ht into SB1 (S/St dead)
#pragma unroll
    for (int rq = 0; rq < 4; ++rq) {
        int cch = wn * 4 + rq;
        u64 q = pack4(aggT[4 * rq + 0], aggT[4 * rq + 1], aggT[4 * rq + 2], aggT[4 * rq + 3]);
        *(u64*)(ab + ecol * 256 + ((cch ^ (ecol & 15)) << 4) + 8 * kg) = q;
    }
    for (int i = tid; i < 1024; i += 512) {
        int row = i >> 4, c = i & 15;
        int node = n0 + row;
        int4v v = zero4();
        if (node < NN) {
            if (use_hb) v = *(const int4v*)(hb + (size_t)node * 128 + c * 8);
            else        v = cvt8(h + (size_t)node * 128 + c * 8);
        }
        *(int4v*)(htp + row * 256 + ((c ^ (row & 15)) << 4)) = v;
    }
    __syncthreads();   // aggL + ht ready (vmcnt drain fine here, once)

    // upd GEMM1 (swapped): au[n1][node] = W1u @ [ht | aggL]^T
    {
        f32x16 au = zero16();
#pragma unroll
        for (int kk = 0; kk < 8; ++kk)
            au = mfma16(wuf[kk], ld256(htp, ecol, kk * 2 + kg), au);
#pragma unroll
        for (int kk = 0; kk < 8; ++kk)
            au = mfma16(wuf[8 + kk], ld256(ab, ecol, kk * 2 + kg), au);
        // epiU1 -> hiddenU[node][n1] into msgt region (256B rows)
#pragma unroll
        for (int rq = 0; rq < 4; ++rq) {
            int cch = wn * 4 + rq;
            u64 q = pack4(fmaxf(au[4 * rq + 0] + b1ur[4 * rq + 0], 0.f),
                          fmaxf(au[4 * rq + 1] + b1ur[4 * rq + 1], 0.f),
                          fmaxf(au[4 * rq + 2] + b1ur[4 * rq + 2], 0.f),
                          fmaxf(au[4 * rq + 3] + b1ur[4 * rq + 3], 0.f));
            *(u64*)(msgt + ecol * 256 + ((cch ^ (ecol & 15)) << 4) + 8 * kg) = q;
        }
    }
    bar_lds();

    // upd GEMM2 (direct): out[node][n2] = hiddenU @ W2u + b2u + h
    {
        f32x16 cu = zero16();
#pragma unroll
        for (int kk = 0; kk < 8; ++kk)
            cu = mfma16(ld256(msgt, ecol, kk * 2 + kg), w2uf[kk], cu);
#pragma unroll
        for (int r = 0; r < 16; ++r) {
            int node = wb * 32 + (r & 3) + 8 * (r >> 2) + 4 * kg;
            int ng = n0 + node;
            if (ng < NN) {
                size_t o = (size_t)ng * 128 + nrow;
                outp[o] = cu[r] + b2us + h[o];
            }
        }
    }
}

extern "C" void kernel_launch(void* const* d_in, const int* in_sizes, int n_in,
                              void* d_out, int out_size, void* d_ws, size_t ws_size,
                              hipStream_t stream) {
    const float* h   = (const float*)d_in[0];
    const int* edges = (const int*)d_in[1];
    const float* W1m = (const float*)d_in[2];
    const float* b1m = (const float*)d_in[3];
    const float* W2m = (const float*)d_in[4];
    const float* b2m = (const float*)d_in[5];
    const float* W1u = (const float*)d_in[6];
    const float* b1u = (const float*)d_in[7];
    const float* W2u = (const float*)d_in[8];
    const float* b2u = (const float*)d_in[9];
    float* out = (float*)d_out;

    char* ws = (char*)d_ws;
    u16* w1tm  = (u16*)(ws + 0);
    u16* w2tm  = (u16*)(ws + 65536);
    u16* w1tu  = (u16*)(ws + 98304);
    u16* w2tu  = (u16*)(ws + 163840);
    int* curs  = (int*)(ws + 196608);
    u32* elist = (u32*)(ws + 200704);    // NT*CAP*4 = 3,203,072
    u16* hb    = (u16*)(ws + 3403776);   // 12,800,000
    int use_hb = (ws_size >= 3403776ull + (size_t)NN * 128 * 2) ? 1 : 0;

    (void)hipFuncSetAttribute((const void*)fused_kernel,
                              hipFuncAttributeMaxDynamicSharedMemorySize, SMEM_TOTAL);

    hipMemsetAsync(curs, 0, NT * sizeof(int), stream);
    prep_kernel<<<512, 256, 0, stream>>>(h, W1m, W2m, W1u, W2u,
                                         w1tm, w2tm, w1tu, w2tu, hb, use_hb);
    scatter_kernel<<<(NE + 2047) / 2048, 256, 0, stream>>>(edges, elist, curs);
    fused_kernel<<<NT, 512, SMEM_TOTAL, stream>>>(h, hb, use_hb, elist, curs,
                                                  w1tm, w2tm, w1tu, w2tu,
                                                  b1m, b2m, b1u, b2u, out);
}